// Round 8
// baseline (449.014 us; speedup 1.0000x reference)
//
#include <hip/hip_runtime.h>
#include <hip/hip_bf16.h>

#define NNODES 100000
#define NEDGES 1600000
#define ALPHA  0.2f
#define EPSV   1e-9f

typedef __bf16 bf16x8 __attribute__((ext_vector_type(8)));
typedef float  f32x4  __attribute__((ext_vector_type(4)));
typedef unsigned short u16x8 __attribute__((ext_vector_type(8)));

// manual RNE f32 -> bf16 bits
static __device__ inline unsigned short f2bf(float f) {
    unsigned int u = __float_as_uint(f);
    unsigned int r = u + 0x7fff + ((u >> 16) & 1);
    return (unsigned short)(r >> 16);
}
static __device__ inline float bf2f(unsigned short v) {
    return __uint_as_float((unsigned int)v << 16);
}

// ---------------- init: head sentinels + W [256][256] f32 -> Wt bf16 (transposed) --
__global__ void k_init(const float* __restrict__ W, unsigned short* __restrict__ Wt,
                       unsigned int* __restrict__ head) {
    const int i = blockIdx.x * 256 + threadIdx.x;
    if (i < NNODES) head[i] = 0xFFFFFFFFu;
    if (i < 65536) {
        const int n = i >> 8, k = i & 255;
        Wt[i] = f2bf(W[k * 256 + n]);
    }
}

// ---------------- bare linked-list build (no label work) ----------------
// 1 thread per edge: push e onto src's chain. rec[e] = {next, dst} (8B, coalesced).
// The exp(leakyrelu(dot)) moved into k_agg (R2-verified structure, +30us there),
// deleting this kernel's 2x128B random label gathers per edge entirely.
__global__ __launch_bounds__(256) void k_chain(const int* __restrict__ src,
                                               const int* __restrict__ dst,
                                               unsigned int* __restrict__ head,
                                               uint2* __restrict__ rec) {
    const int e = blockIdx.x * 256 + threadIdx.x;
    if (e >= NEDGES) return;
    const int s = src[e];
    const unsigned int old = atomicExch(&head[s], (unsigned int)e);
    rec[e] = make_uint2(old, (unsigned int)dst[e]);
}

// ---------------- bf16 MFMA GEMM: Wh = h @ W (verified round-0 form) ----------------
#define BM 128
#define BK 32
#define LSTRIDE 40
__global__ __launch_bounds__(256, 2) void k_gemm(const float* __restrict__ h,
                                                 const unsigned short* __restrict__ Wt,
                                                 unsigned short* __restrict__ Wh) {
    __shared__ __align__(16) unsigned short As[BM * LSTRIDE];
    __shared__ __align__(16) unsigned short Bs[256 * LSTRIDE];
    const int tid  = threadIdx.x;
    const int m0   = blockIdx.x * BM;
    const int wave = tid >> 6;
    const int lane = tid & 63;
    const int wm = (wave & 1) * 64;
    const int wn = (wave >> 1) * 128;
    const int fm = lane & 15;
    const int fq = lane >> 4;
    const int fk = fq * 8;

    f32x4 acc[4][8];
    const f32x4 z = {0.f, 0.f, 0.f, 0.f};
#pragma unroll
    for (int i = 0; i < 4; ++i)
#pragma unroll
        for (int j = 0; j < 8; ++j) acc[i][j] = z;

    const int arow = tid >> 1;
    const int acol = (tid & 1) * 16;
    const bool arow_ok = (m0 + arow) < NNODES;
    const float* hrow = h + (size_t)(m0 + arow) * 256 + acol;

    for (int kc = 0; kc < 256; kc += BK) {
        float4 a0, a1, a2, a3;
        if (arow_ok) {
            a0 = *(const float4*)(hrow + kc + 0);
            a1 = *(const float4*)(hrow + kc + 4);
            a2 = *(const float4*)(hrow + kc + 8);
            a3 = *(const float4*)(hrow + kc + 12);
        } else {
            a0 = a1 = a2 = a3 = make_float4(0.f, 0.f, 0.f, 0.f);
        }
        u16x8 bv[4];
#pragma unroll
        for (int q = 0; q < 4; ++q) {
            const int c = tid + 256 * q;
            const int n = c >> 2, koff = (c & 3) * 8;
            bv[q] = *(const u16x8*)(Wt + n * 256 + kc + koff);
        }
        __syncthreads();
        u16x8 p0, p1;
        p0[0]=f2bf(a0.x); p0[1]=f2bf(a0.y); p0[2]=f2bf(a0.z); p0[3]=f2bf(a0.w);
        p0[4]=f2bf(a1.x); p0[5]=f2bf(a1.y); p0[6]=f2bf(a1.z); p0[7]=f2bf(a1.w);
        p1[0]=f2bf(a2.x); p1[1]=f2bf(a2.y); p1[2]=f2bf(a2.z); p1[3]=f2bf(a2.w);
        p1[4]=f2bf(a3.x); p1[5]=f2bf(a3.y); p1[6]=f2bf(a3.z); p1[7]=f2bf(a3.w);
        *(u16x8*)&As[arow * LSTRIDE + acol]     = p0;
        *(u16x8*)&As[arow * LSTRIDE + acol + 8] = p1;
#pragma unroll
        for (int q = 0; q < 4; ++q) {
            const int c = tid + 256 * q;
            const int n = c >> 2, koff = (c & 3) * 8;
            *(u16x8*)&Bs[n * LSTRIDE + koff] = bv[q];
        }
        __syncthreads();
        bf16x8 af[4], bfr[8];
#pragma unroll
        for (int i = 0; i < 4; ++i)
            af[i] = __builtin_bit_cast(bf16x8,
                *(const u16x8*)&As[(wm + 16 * i + fm) * LSTRIDE + fk]);
#pragma unroll
        for (int j = 0; j < 8; ++j)
            bfr[j] = __builtin_bit_cast(bf16x8,
                *(const u16x8*)&Bs[(wn + 16 * j + fm) * LSTRIDE + fk]);
#pragma unroll
        for (int i = 0; i < 4; ++i)
#pragma unroll
            for (int j = 0; j < 8; ++j)
                acc[i][j] = __builtin_amdgcn_mfma_f32_16x16x32_bf16(af[i], bfr[j], acc[i][j], 0, 0, 0);
    }
#pragma unroll
    for (int i = 0; i < 4; ++i) {
#pragma unroll
        for (int r = 0; r < 4; ++r) {
            const int grow = m0 + wm + 16 * i + fq * 4 + r;
            if (grow < NNODES) {
                unsigned short* orow = Wh + (size_t)grow * 256 + wn + fm;
#pragma unroll
                for (int j = 0; j < 8; ++j)
                    orow[16 * j] = f2bf(acc[i][j][r]);
            }
        }
    }
}

// ---------------- fused attention + aggregation over chains ----------------
// 32 lanes per node (R6-verified walk + R2-verified in-loop dot).
// sub = lane&31 owns Wh/out channels [sub*8, +8); lane holds label channels
// [(sub&7)*4, +4). Per chain step: 8B rec broadcast -> label[d] gather (128B,
// 4 groups redundant/coalesced) + Wh[d] gather (512B); dot via 3x shfl_xor in
// the 8-lane group (all lanes end with the full dot), leakyrelu+exp, FMA.
__global__ __launch_bounds__(256) void k_agg(const unsigned short* __restrict__ Wh,
                                             const float* __restrict__ label,
                                             const unsigned int* __restrict__ head,
                                             const uint2* __restrict__ rec,
                                             float* __restrict__ out) {
    const int node = blockIdx.x * 8 + (threadIdx.x >> 5);
    if (node >= NNODES) return;
    const int sub = threadIdx.x & 31;
    const int c4 = (sub & 7) * 4;
    const unsigned short* __restrict__ Whc = Wh + sub * 8;

    const float4 lsv = *(const float4*)&label[(size_t)node * 32 + c4];

    float acc[8] = {0.f, 0.f, 0.f, 0.f, 0.f, 0.f, 0.f, 0.f};
    float wsum = 0.f;
    unsigned int cur = head[node];
    while (cur != 0xFFFFFFFFu) {
        const uint2 p = rec[cur];
        const unsigned int d = p.y;
        const float4 ldv = *(const float4*)&label[(size_t)d * 32 + c4];
        const u16x8 v = *(const u16x8*)&Whc[(size_t)d * 256];
        float dot = lsv.x * ldv.x + lsv.y * ldv.y + lsv.z * ldv.z + lsv.w * ldv.w;
        dot += __shfl_xor(dot, 1);
        dot += __shfl_xor(dot, 2);
        dot += __shfl_xor(dot, 4);        // full 32-ch dot in every lane of the group
        const float lr = fmaxf(dot, ALPHA * dot);
        const float w = expf(lr);
        wsum += w;
#pragma unroll
        for (int c = 0; c < 8; ++c) acc[c] = fmaf(w, bf2f(v[c]), acc[c]);
        cur = p.x;
    }
    const float inv = 1.f / fmaxf(wsum, EPSV);
    float4 o0 = make_float4(acc[0] * inv, acc[1] * inv, acc[2] * inv, acc[3] * inv);
    float4 o1 = make_float4(acc[4] * inv, acc[5] * inv, acc[6] * inv, acc[7] * inv);
    float* orow = out + (size_t)node * 256 + sub * 8;
    *(float4*)(orow + 0) = o0;
    *(float4*)(orow + 4) = o1;
}

extern "C" void kernel_launch(void* const* d_in, const int* in_sizes, int n_in,
                              void* d_out, int out_size, void* d_ws, size_t ws_size,
                              hipStream_t stream) {
    const float* h     = (const float*)d_in[0];   // [N,256]
    const float* label = (const float*)d_in[1];   // [N,32]
    const float* W     = (const float*)d_in[2];   // [256,256]
    const int*   adj   = (const int*)d_in[3];     // [2,E]
    const int* src = adj;
    const int* dst = adj + NEDGES;
    float* out = (float*)d_out;

    // workspace layout (bytes)
    char* ws = (char*)d_ws;
    unsigned short* Wh   = (unsigned short*)(ws + 0);          // N*256*2  = 51,200,000
    unsigned short* Wt   = (unsigned short*)(ws + 51200000);   // 256*256*2 = 131,072
    uint2*        rec    = (uint2*)        (ws + 51400000);    // E*8 = 12,800,000
    unsigned int* head   = (unsigned int*) (ws + 64200000);    // N*4 = 400,000

    k_init<<<392, 256, 0, stream>>>(W, Wt, head);
    k_chain<<<(NEDGES + 255) / 256, 256, 0, stream>>>(src, dst, head, rec);
    k_gemm<<<(NNODES + BM - 1) / BM, 256, 0, stream>>>(h, Wt, Wh);
    k_agg<<<(NNODES + 7) / 8, 256, 0, stream>>>(Wh, label, head, rec, out);
}

// Round 9
// 425.170 us; speedup vs baseline: 1.0561x; 1.0561x over previous
//
#include <hip/hip_runtime.h>
#include <hip/hip_bf16.h>

#define NNODES 100000
#define NEDGES 1600000
#define ALPHA  0.2f
#define EPSV   1e-9f

#define HPAD   16              // head padding: 16 ints = 64B per node
#define SENT21 0x1FFFFFu       // 21-bit chain terminator

typedef __bf16 bf16x8 __attribute__((ext_vector_type(8)));
typedef float  f32x4  __attribute__((ext_vector_type(4)));
typedef unsigned short u16x8 __attribute__((ext_vector_type(8)));

// manual RNE f32 -> bf16 bits
static __device__ inline unsigned short f2bf(float f) {
    unsigned int u = __float_as_uint(f);
    unsigned int r = u + 0x7fff + ((u >> 16) & 1);
    return (unsigned short)(r >> 16);
}
static __device__ inline float bf2f(unsigned short v) {
    return __uint_as_float((unsigned int)v << 16);
}

// ---------------- init: padded head sentinels + W -> Wt bf16 (transposed) ----------
__global__ void k_init(const float* __restrict__ W, unsigned short* __restrict__ Wt,
                       unsigned int* __restrict__ head) {
    const int i = blockIdx.x * 256 + threadIdx.x;
    if (i < NNODES * HPAD) head[i] = 0xFFFFFFFFu;
    if (i < 65536) {
        const int n = i >> 8, k = i & 255;
        Wt[i] = f2bf(W[k * 256 + n]);
    }
}

// ---------------- bf16 MFMA GEMM: Wh = h @ W (verified round-0 form) ----------------
#define BM 128
#define BK 32
#define LSTRIDE 40
__global__ __launch_bounds__(256, 2) void k_gemm(const float* __restrict__ h,
                                                 const unsigned short* __restrict__ Wt,
                                                 unsigned short* __restrict__ Wh) {
    __shared__ __align__(16) unsigned short As[BM * LSTRIDE];
    __shared__ __align__(16) unsigned short Bs[256 * LSTRIDE];
    const int tid  = threadIdx.x;
    const int m0   = blockIdx.x * BM;
    const int wave = tid >> 6;
    const int lane = tid & 63;
    const int wm = (wave & 1) * 64;
    const int wn = (wave >> 1) * 128;
    const int fm = lane & 15;
    const int fq = lane >> 4;
    const int fk = fq * 8;

    f32x4 acc[4][8];
    const f32x4 z = {0.f, 0.f, 0.f, 0.f};
#pragma unroll
    for (int i = 0; i < 4; ++i)
#pragma unroll
        for (int j = 0; j < 8; ++j) acc[i][j] = z;

    const int arow = tid >> 1;
    const int acol = (tid & 1) * 16;
    const bool arow_ok = (m0 + arow) < NNODES;
    const float* hrow = h + (size_t)(m0 + arow) * 256 + acol;

    for (int kc = 0; kc < 256; kc += BK) {
        float4 a0, a1, a2, a3;
        if (arow_ok) {
            a0 = *(const float4*)(hrow + kc + 0);
            a1 = *(const float4*)(hrow + kc + 4);
            a2 = *(const float4*)(hrow + kc + 8);
            a3 = *(const float4*)(hrow + kc + 12);
        } else {
            a0 = a1 = a2 = a3 = make_float4(0.f, 0.f, 0.f, 0.f);
        }
        u16x8 bv[4];
#pragma unroll
        for (int q = 0; q < 4; ++q) {
            const int c = tid + 256 * q;
            const int n = c >> 2, koff = (c & 3) * 8;
            bv[q] = *(const u16x8*)(Wt + n * 256 + kc + koff);
        }
        __syncthreads();
        u16x8 p0, p1;
        p0[0]=f2bf(a0.x); p0[1]=f2bf(a0.y); p0[2]=f2bf(a0.z); p0[3]=f2bf(a0.w);
        p0[4]=f2bf(a1.x); p0[5]=f2bf(a1.y); p0[6]=f2bf(a1.z); p0[7]=f2bf(a1.w);
        p1[0]=f2bf(a2.x); p1[1]=f2bf(a2.y); p1[2]=f2bf(a2.z); p1[3]=f2bf(a2.w);
        p1[4]=f2bf(a3.x); p1[5]=f2bf(a3.y); p1[6]=f2bf(a3.z); p1[7]=f2bf(a3.w);
        *(u16x8*)&As[arow * LSTRIDE + acol]     = p0;
        *(u16x8*)&As[arow * LSTRIDE + acol + 8] = p1;
#pragma unroll
        for (int q = 0; q < 4; ++q) {
            const int c = tid + 256 * q;
            const int n = c >> 2, koff = (c & 3) * 8;
            *(u16x8*)&Bs[n * LSTRIDE + koff] = bv[q];
        }
        __syncthreads();
        bf16x8 af[4], bfr[8];
#pragma unroll
        for (int i = 0; i < 4; ++i)
            af[i] = __builtin_bit_cast(bf16x8,
                *(const u16x8*)&As[(wm + 16 * i + fm) * LSTRIDE + fk]);
#pragma unroll
        for (int j = 0; j < 8; ++j)
            bfr[j] = __builtin_bit_cast(bf16x8,
                *(const u16x8*)&Bs[(wn + 16 * j + fm) * LSTRIDE + fk]);
#pragma unroll
        for (int i = 0; i < 4; ++i)
#pragma unroll
            for (int j = 0; j < 8; ++j)
                acc[i][j] = __builtin_amdgcn_mfma_f32_16x16x32_bf16(af[i], bfr[j], acc[i][j], 0, 0, 0);
    }
#pragma unroll
    for (int i = 0; i < 4; ++i) {
#pragma unroll
        for (int r = 0; r < 4; ++r) {
            const int grow = m0 + wm + 16 * i + fq * 4 + r;
            if (grow < NNODES) {
                unsigned short* orow = Wh + (size_t)grow * 256 + wn + fm;
#pragma unroll
                for (int j = 0; j < 8; ++j)
                    orow[16 * j] = f2bf(acc[i][j][r]);
            }
        }
    }
}

// ---------------- attention + linked-list build (R6 form, padded heads) ------------
// 4 lanes/edge, quad shuffle reduce (verified). Lane 0: w = exp(leakyrelu(dot)),
// push e onto src's chain via atomicExch on a 64B-padded head slot (tests the
// line-serialization hypothesis: packed heads = 256 RMW ops/line; padded = 16).
// rec[e] packs {next:21|wlo:11, dst:17|whi:15}; w kept to 26 bits of f32
// (sign+exp+17 mantissa, rel err ~8e-6).
__global__ __launch_bounds__(256) void k_attn_chain(const float* __restrict__ label,
                                                    const int* __restrict__ src,
                                                    const int* __restrict__ dst,
                                                    unsigned int* __restrict__ head,
                                                    uint2* __restrict__ rec) {
    const int t = blockIdx.x * 256 + threadIdx.x;
    const int e = t >> 2;            // edge id
    const int l4 = t & 3;            // lane within quad
    if (e >= NEDGES) return;
    const int s = src[e], d = dst[e];
    const float4* ls = (const float4*)&label[s * 32 + l4 * 8];
    const float4* ld = (const float4*)&label[d * 32 + l4 * 8];
    const float4 a0 = ls[0], a1 = ls[1];
    const float4 b0 = ld[0], b1 = ld[1];
    float dot = a0.x * b0.x + a0.y * b0.y + a0.z * b0.z + a0.w * b0.w
              + a1.x * b1.x + a1.y * b1.y + a1.z * b1.z + a1.w * b1.w;
    dot += __shfl_xor(dot, 1);
    dot += __shfl_xor(dot, 2);
    if (l4 == 0) {
        const float lr = dot >= 0.f ? dot : ALPHA * dot;
        const float w = expf(lr);
        const unsigned int w26 = __float_as_uint(w) >> 6;     // 26 bits kept
        const unsigned int wlo = w26 & 0x7FFu;                // low 11
        const unsigned int whi = w26 >> 11;                   // high 15
        const unsigned int old = atomicExch(&head[(size_t)s * HPAD], (unsigned int)e);
        const unsigned int nxt = old & SENT21;   // sentinel 0xFFFFFFFF -> 0x1FFFFF
        rec[e] = make_uint2(nxt | (wlo << 21), (unsigned int)d | (whi << 17));
    }
}

// ---------------- aggregation: chain walk, 32 lanes/node (R6-verified) -------------
__global__ __launch_bounds__(256) void k_aggregate(const unsigned short* __restrict__ Wh,
                                                   const unsigned int* __restrict__ head,
                                                   const uint2* __restrict__ rec,
                                                   float* __restrict__ out) {
    const int node = blockIdx.x * 8 + (threadIdx.x >> 5);
    if (node >= NNODES) return;
    const int sub = threadIdx.x & 31;      // owns channels [sub*8, sub*8+8)
    const unsigned short* __restrict__ Whc = Wh + sub * 8;
    float acc[8] = {0.f, 0.f, 0.f, 0.f, 0.f, 0.f, 0.f, 0.f};
    float wsum = 0.f;
    unsigned int cur = head[(size_t)node * HPAD] & SENT21;
    while (cur != SENT21) {
        const uint2 p = rec[cur];
        const unsigned int d   = p.y & 0x1FFFFu;
        const unsigned int w26 = ((p.y >> 17) << 11) | (p.x >> 21);
        const float w = __uint_as_float(w26 << 6);
        const u16x8 v = *(const u16x8*)&Whc[(size_t)d * 256];
        wsum += w;
#pragma unroll
        for (int c = 0; c < 8; ++c) acc[c] = fmaf(w, bf2f(v[c]), acc[c]);
        cur = p.x & SENT21;
    }
    const float inv = 1.f / fmaxf(wsum, EPSV);
    float4 o0 = make_float4(acc[0] * inv, acc[1] * inv, acc[2] * inv, acc[3] * inv);
    float4 o1 = make_float4(acc[4] * inv, acc[5] * inv, acc[6] * inv, acc[7] * inv);
    float* orow = out + (size_t)node * 256 + sub * 8;
    *(float4*)(orow + 0) = o0;
    *(float4*)(orow + 4) = o1;
}

extern "C" void kernel_launch(void* const* d_in, const int* in_sizes, int n_in,
                              void* d_out, int out_size, void* d_ws, size_t ws_size,
                              hipStream_t stream) {
    const float* h     = (const float*)d_in[0];   // [N,256]
    const float* label = (const float*)d_in[1];   // [N,32]
    const float* W     = (const float*)d_in[2];   // [256,256]
    const int*   adj   = (const int*)d_in[3];     // [2,E]
    const int* src = adj;
    const int* dst = adj + NEDGES;
    float* out = (float*)d_out;

    // workspace layout (bytes)
    char* ws = (char*)d_ws;
    unsigned short* Wh   = (unsigned short*)(ws + 0);          // N*256*2  = 51,200,000
    unsigned short* Wt   = (unsigned short*)(ws + 51200000);   // 256*256*2 = 131,072
    uint2*        rec    = (uint2*)        (ws + 51400000);    // E*8 = 12,800,000
    unsigned int* head   = (unsigned int*) (ws + 64200000);    // N*16*4 = 6,400,000 (64B/node)

    k_init<<<(NNODES * HPAD + 255) / 256, 256, 0, stream>>>(W, Wt, head);
    k_gemm<<<(NNODES + BM - 1) / BM, 256, 0, stream>>>(h, Wt, Wh);
    k_attn_chain<<<(4 * NEDGES + 255) / 256, 256, 0, stream>>>(label, src, dst, head, rec);
    k_aggregate<<<(NNODES + 7) / 8, 256, 0, stream>>>(Wh, head, rec, out);
}